// Round 1
// baseline (322.534 us; speedup 1.0000x reference)
//
#include <hip/hip_runtime.h>
#include <math.h>

#define B_TOT 4096
#define T_LEN 200
#define E_DIM 12
#define BPB   5   // batches per block

// d_ws layout (floats):
//  row o (o in 0..79), stride 80:
//   [o*80 +  0..11] : Wk_eff[i][o]  = W0[12+i][o] - W0[24+i][o]
//   [o*80 + 12..23] : Wqk[i][o]     = W0[36+i][o]
//   [o*80 + 24..63] : W1[o][j], j = 0..39
//   [o*80 + 64]     : mm0[o]
//   [o*80 + 65]     : rsqrt(mv0[o] + eps)
//   [o*80 + 66]     : alpha0[o]
//  [6400 + j*8 + {0..4}] : b1[j], mm1[j], rsqrt(mv1[j]+eps), alpha1[j], ak[j]
//  [6720 + i*80 + o]     : Wq_eff[i][o] = W0[i][o] + W0[24+i][o]

__global__ __launch_bounds__(128) void din_prep(
    const float* __restrict__ W0, const float* __restrict__ W1,
    const float* __restrict__ b1v, const float* __restrict__ a0,
    const float* __restrict__ a1, const float* __restrict__ mm0,
    const float* __restrict__ mv0, const float* __restrict__ mm1,
    const float* __restrict__ mv1, const float* __restrict__ ak,
    float* __restrict__ ws)
{
    const int tid = threadIdx.x;
    for (int o = tid; o < 80; o += 128) {
        float* row = ws + o * 80;
        #pragma unroll
        for (int i = 0; i < 12; ++i)
            row[i] = W0[(12 + i) * 80 + o] - W0[(24 + i) * 80 + o];
        #pragma unroll
        for (int i = 0; i < 12; ++i)
            row[12 + i] = W0[(36 + i) * 80 + o];
        #pragma unroll
        for (int j = 0; j < 40; ++j)
            row[24 + j] = W1[o * 40 + j];
        row[64] = mm0[o];
        row[65] = rsqrtf(mv0[o] + 1e-9f);
        row[66] = a0[o];
    }
    for (int j = tid; j < 40; j += 128) {
        float* r2 = ws + 6400 + j * 8;
        r2[0] = b1v[j];
        r2[1] = mm1[j];
        r2[2] = rsqrtf(mv1[j] + 1e-9f);
        r2[3] = a1[j];
        r2[4] = ak[j];
    }
    for (int v = tid; v < 960; v += 128) {
        int i = v / 80, o = v % 80;
        ws[6720 + v] = W0[i * 80 + o] + W0[(24 + i) * 80 + o];
    }
}

__global__ __launch_bounds__(256) void din_main(
    const float* __restrict__ query, const float* __restrict__ keys,
    const float* __restrict__ b0v, const float* __restrict__ abias_p,
    const float* __restrict__ ws, float* __restrict__ out)
{
    __shared__ float z0q[BPB * 81];      // q-projection + b0, padded stride 81
    __shared__ float qsh[BPB * 12];
    __shared__ float score[BPB * T_LEN];
    __shared__ float oacc[BPB * 12];

    const int tid = threadIdx.x;
    const int b0idx = blockIdx.x * BPB;
    const int nb = min(BPB, B_TOT - b0idx);

    // ---- phase 0: stage q, init output accumulators ----
    if (tid < BPB * 12) oacc[tid] = 0.0f;
    if (tid < nb * 12) {
        int bl = tid / 12, i = tid % 12;
        qsh[bl * 12 + i] = query[(size_t)(b0idx + bl) * 12 + i];
    }
    __syncthreads();

    // ---- per-b q projection: z0q[bl][o] = b0[o] + sum_i q[i]*Wq_eff[i][o] ----
    for (int v = tid; v < nb * 80; v += 256) {
        int bl = v / 80, o = v - bl * 80;
        float z = b0v[o];
        #pragma unroll
        for (int i = 0; i < 12; ++i)
            z += qsh[bl * 12 + i] * ws[6720 + i * 80 + o];
        z0q[bl * 81 + o] = z;
    }
    __syncthreads();

    const float abias = abias_p[0];
    const int npos = nb * T_LEN;

    // ---- phase 1: per-position MLP ----
    for (int p = tid; p < npos; p += 256) {
        int bl = p / T_LEN, t = p - bl * T_LEN;
        size_t kbase = ((size_t)(b0idx + bl) * T_LEN + t) * E_DIM;
        float k[12], qk[12];
        {
            const float4* kp = (const float4*)(keys + kbase);
            float4 k0 = kp[0], k1 = kp[1], k2 = kp[2];
            k[0] = k0.x; k[1] = k0.y; k[2] = k0.z; k[3] = k0.w;
            k[4] = k1.x; k[5] = k1.y; k[6] = k1.z; k[7] = k1.w;
            k[8] = k2.x; k[9] = k2.y; k[10] = k2.z; k[11] = k2.w;
        }
        #pragma unroll
        for (int i = 0; i < 12; ++i)
            qk[i] = qsh[bl * 12 + i] * k[i];

        float z1[40];
        #pragma unroll
        for (int j = 0; j < 40; ++j)
            z1[j] = ws[6400 + j * 8 + 0];   // b1[j], uniform -> scalar load

        for (int o = 0; o < 80; ++o) {
            const float* row = ws + o * 80;   // uniform base -> s_loads
            float z = z0q[bl * 81 + o];
            #pragma unroll
            for (int i = 0; i < 12; ++i) z += k[i] * row[i];
            #pragma unroll
            for (int i = 0; i < 12; ++i) z += qk[i] * row[12 + i];
            // Dice 0
            float zn = (z - row[64]) * row[65];
            float pg = 1.0f / (1.0f + __expf(-zn));
            float a = row[66];
            float h = z * (a + pg * (1.0f - a));
            // fused layer 1 broadcast
            #pragma unroll
            for (int j = 0; j < 40; ++j)
                z1[j] += h * row[24 + j];
        }

        float sc = abias;
        #pragma unroll
        for (int j = 0; j < 40; ++j) {
            const float* r2 = ws + 6400 + j * 8;  // uniform -> s_loads
            float zn = (z1[j] - r2[1]) * r2[2];
            float pg = 1.0f / (1.0f + __expf(-zn));
            float a = r2[3];
            float h = z1[j] * (a + pg * (1.0f - a));
            sc += h * r2[4];
        }
        score[bl * T_LEN + t] = sc;
    }
    __syncthreads();

    // ---- phase 2: out[b][e] = sum_t score[t] * keys[b][t][e] ----
    // 48 threads per b: 4 T-slices x 12 e
    if (tid < nb * 48) {
        int bl = tid / 48, r = tid - bl * 48;
        int sub = r / 12, e = r - sub * 12;
        size_t b = (size_t)(b0idx + bl);
        float acc = 0.0f;
        int t0 = sub * 50;
        for (int t = t0; t < t0 + 50; ++t)
            acc += score[bl * T_LEN + t] * keys[(b * T_LEN + t) * E_DIM + e];
        atomicAdd(&oacc[bl * 12 + e], acc);
    }
    __syncthreads();
    if (tid < nb * 12) {
        int bl = tid / 12, e = tid - bl * 12;
        out[(size_t)(b0idx + bl) * 12 + e] = oacc[bl * 12 + e];
    }
}

extern "C" void kernel_launch(void* const* d_in, const int* in_sizes, int n_in,
                              void* d_out, int out_size, void* d_ws, size_t ws_size,
                              hipStream_t stream) {
    const float* query = (const float*)d_in[0];
    const float* keys  = (const float*)d_in[1];
    // d_in[2] = mask (unused: reference bug matmuls unmasked scores)
    const float* W0  = (const float*)d_in[3];
    const float* b0v = (const float*)d_in[4];
    const float* W1  = (const float*)d_in[5];
    const float* b1v = (const float*)d_in[6];
    const float* a0  = (const float*)d_in[7];
    const float* a1  = (const float*)d_in[8];
    const float* mm0 = (const float*)d_in[9];
    const float* mv0 = (const float*)d_in[10];
    const float* mm1 = (const float*)d_in[11];
    const float* mv1 = (const float*)d_in[12];
    const float* ak  = (const float*)d_in[13];
    const float* ab  = (const float*)d_in[14];
    float* out = (float*)d_out;
    float* ws  = (float*)d_ws;

    hipLaunchKernelGGL(din_prep, dim3(1), dim3(128), 0, stream,
                       W0, W1, b1v, a0, a1, mm0, mv0, mm1, mv1, ak, ws);
    const int nblocks = (B_TOT + BPB - 1) / BPB;  // 820
    hipLaunchKernelGGL(din_main, dim3(nblocks), dim3(256), 0, stream,
                       query, keys, b0v, ab, ws, out);
}

// Round 2
// 277.046 us; speedup vs baseline: 1.1642x; 1.1642x over previous
//
#include <hip/hip_runtime.h>
#include <math.h>

#define B_TOT 4096
#define T_LEN 200
#define E_DIM 12
#define BPB   5   // batches per block
#define LOG2E 1.44269504088896340736f

// d_ws layout (floats):
//  row o (o in 0..79), stride 80:
//   [o*80 +  0..11] : Wk_eff[i][o]  = W0[12+i][o] - W0[24+i][o]
//   [o*80 + 12..23] : Wqk[i][o]     = W0[36+i][o]
//   [o*80 + 24..63] : W1[o][j], j = 0..39
//   [o*80 + 64]     : nrs0 = -rsqrt(mv0+eps)*log2e
//   [o*80 + 65]     : pmr0 = mm0*rsqrt(mv0+eps)*log2e
//   [o*80 + 66]     : a0
//   [o*80 + 67]     : 1 - a0
//  [6400 + j*8 + {0..4}] : b1[j], nrs1, pmr1, c0=a1*ak, c1=(1-a1)*ak
//  [6720 + i*80 + o]     : Wq_eff[i][o] = W0[i][o] + W0[24+i][o]

__global__ __launch_bounds__(256) void din_prep(
    const float* __restrict__ W0, const float* __restrict__ W1,
    const float* __restrict__ b1v, const float* __restrict__ a0,
    const float* __restrict__ a1, const float* __restrict__ mm0,
    const float* __restrict__ mv0, const float* __restrict__ mm1,
    const float* __restrict__ mv1, const float* __restrict__ ak,
    float* __restrict__ ws)
{
    int idx = blockIdx.x * 256 + threadIdx.x;
    if (idx < 960) {                         // A: Wk_eff
        int o = idx / 12, i = idx % 12;
        ws[o * 80 + i] = W0[(12 + i) * 80 + o] - W0[(24 + i) * 80 + o];
    } else if (idx < 1920) {                 // B: Wqk
        int v = idx - 960;
        int o = v / 12, i = v % 12;
        ws[o * 80 + 12 + i] = W0[(36 + i) * 80 + o];
    } else if (idx < 5120) {                 // C: W1 copy
        int v = idx - 1920;
        int o = v / 40, j = v % 40;
        ws[o * 80 + 24 + j] = W1[o * 40 + j];
    } else if (idx < 5200) {                 // D: dice0 consts
        int o = idx - 5120;
        float rs = rsqrtf(mv0[o] + 1e-9f) * LOG2E;
        ws[o * 80 + 64] = -rs;
        ws[o * 80 + 65] = mm0[o] * rs;
        ws[o * 80 + 66] = a0[o];
        ws[o * 80 + 67] = 1.0f - a0[o];
    } else if (idx < 5240) {                 // E: layer1 consts
        int j = idx - 5200;
        float* r2 = ws + 6400 + j * 8;
        float rs = rsqrtf(mv1[j] + 1e-9f) * LOG2E;
        r2[0] = b1v[j];
        r2[1] = -rs;
        r2[2] = mm1[j] * rs;
        r2[3] = a1[j] * ak[j];
        r2[4] = (1.0f - a1[j]) * ak[j];
    } else if (idx < 6200) {                 // F: Wq_eff
        int v = idx - 5240;
        int i = v / 80, o = v % 80;
        ws[6720 + v] = W0[i * 80 + o] + W0[(24 + i) * 80 + o];
    }
}

__global__ __launch_bounds__(256, 4) void din_main(
    const float* __restrict__ query, const float* __restrict__ keys,
    const float* __restrict__ b0v, const float* __restrict__ abias_p,
    const float* __restrict__ ws, float* __restrict__ out)
{
    __shared__ float z0q[BPB * 81];      // q-projection + b0, padded stride 81
    __shared__ float qsh[BPB * 12];
    __shared__ float score[BPB * T_LEN];
    __shared__ float oacc[BPB * 12];

    const int tid = threadIdx.x;
    const int b0idx = blockIdx.x * BPB;
    const int nb = min(BPB, B_TOT - b0idx);

    // ---- phase 0: stage q, init output accumulators ----
    if (tid < BPB * 12) oacc[tid] = 0.0f;
    if (tid < nb * 12) {
        int bl = tid / 12, i = tid % 12;
        qsh[bl * 12 + i] = query[(size_t)(b0idx + bl) * 12 + i];
    }
    __syncthreads();

    // ---- per-b q projection: z0q[bl][o] = b0[o] + sum_i q[i]*Wq_eff[i][o] ----
    for (int v = tid; v < nb * 80; v += 256) {
        int bl = v / 80, o = v - bl * 80;
        float z = b0v[o];
        #pragma unroll
        for (int i = 0; i < 12; ++i)
            z = fmaf(qsh[bl * 12 + i], ws[6720 + i * 80 + o], z);
        z0q[bl * 81 + o] = z;
    }
    __syncthreads();

    const float abias = abias_p[0];
    const int npos = nb * T_LEN;

    // ---- phase 1: per-position MLP ----
    for (int p = tid; p < npos; p += 256) {
        int bl = p / T_LEN, t = p - bl * T_LEN;
        size_t kbase = ((size_t)(b0idx + bl) * T_LEN + t) * E_DIM;
        float k[12], qk[12];
        {
            const float4* kp = (const float4*)(keys + kbase);
            float4 k0 = kp[0], k1 = kp[1], k2 = kp[2];
            k[0] = k0.x; k[1] = k0.y; k[2] = k0.z; k[3] = k0.w;
            k[4] = k1.x; k[5] = k1.y; k[6] = k1.z; k[7] = k1.w;
            k[8] = k2.x; k[9] = k2.y; k[10] = k2.z; k[11] = k2.w;
        }
        #pragma unroll
        for (int i = 0; i < 12; ++i)
            qk[i] = qsh[bl * 12 + i] * k[i];

        float z1[40];
        #pragma unroll
        for (int j = 0; j < 40; ++j)
            z1[j] = ws[6400 + j * 8 + 0];   // b1[j], uniform -> scalar load

        for (int o = 0; o < 80; ++o) {
            const float* row = ws + o * 80;   // uniform base -> s_loads
            float z = z0q[bl * 81 + o];
            #pragma unroll
            for (int i = 0; i < 12; ++i) z = fmaf(k[i], row[i], z);
            #pragma unroll
            for (int i = 0; i < 12; ++i) z = fmaf(qk[i], row[12 + i], z);
            // Dice 0: 6 VALU ops (2 trans)
            float tt = fmaf(z, row[64], row[65]);
            float e  = __builtin_amdgcn_exp2f(tt);
            float pg = __builtin_amdgcn_rcpf(1.0f + e);
            float g  = fmaf(pg, row[67], row[66]);
            float h  = z * g;
            // fused layer 1 broadcast
            #pragma unroll
            for (int j = 0; j < 40; ++j)
                z1[j] = fmaf(h, row[24 + j], z1[j]);
        }

        float sc = abias;
        #pragma unroll
        for (int j = 0; j < 40; ++j) {
            const float* r2 = ws + 6400 + j * 8;  // uniform -> s_loads
            float z  = z1[j];
            float tt = fmaf(z, r2[1], r2[2]);
            float e  = __builtin_amdgcn_exp2f(tt);
            float pg = __builtin_amdgcn_rcpf(1.0f + e);
            float s  = fmaf(pg, r2[4], r2[3]);
            sc = fmaf(z, s, sc);
        }
        score[bl * T_LEN + t] = sc;
    }
    __syncthreads();

    // ---- phase 2: out[b][e] = sum_t score[t] * keys[b][t][e] ----
    if (tid < nb * 48) {
        int bl = tid / 48, r = tid - bl * 48;
        int sub = r / 12, e = r - sub * 12;
        size_t b = (size_t)(b0idx + bl);
        float acc = 0.0f;
        int t0 = sub * 50;
        for (int t = t0; t < t0 + 50; ++t)
            acc = fmaf(score[bl * T_LEN + t], keys[(b * T_LEN + t) * E_DIM + e], acc);
        atomicAdd(&oacc[bl * 12 + e], acc);
    }
    __syncthreads();
    if (tid < nb * 12) {
        int bl = tid / 12, e = tid - bl * 12;
        out[(size_t)(b0idx + bl) * 12 + e] = oacc[bl * 12 + e];
    }
}

extern "C" void kernel_launch(void* const* d_in, const int* in_sizes, int n_in,
                              void* d_out, int out_size, void* d_ws, size_t ws_size,
                              hipStream_t stream) {
    const float* query = (const float*)d_in[0];
    const float* keys  = (const float*)d_in[1];
    // d_in[2] = mask (unused: reference bug matmuls unmasked scores)
    const float* W0  = (const float*)d_in[3];
    const float* b0v = (const float*)d_in[4];
    const float* W1  = (const float*)d_in[5];
    const float* b1v = (const float*)d_in[6];
    const float* a0  = (const float*)d_in[7];
    const float* a1  = (const float*)d_in[8];
    const float* mm0 = (const float*)d_in[9];
    const float* mv0 = (const float*)d_in[10];
    const float* mm1 = (const float*)d_in[11];
    const float* mv1 = (const float*)d_in[12];
    const float* ak  = (const float*)d_in[13];
    const float* ab  = (const float*)d_in[14];
    float* out = (float*)d_out;
    float* ws  = (float*)d_ws;

    hipLaunchKernelGGL(din_prep, dim3(25), dim3(256), 0, stream,
                       W0, W1, b1v, a0, a1, mm0, mv0, mm1, mv1, ak, ws);
    const int nblocks = (B_TOT + BPB - 1) / BPB;  // 820
    hipLaunchKernelGGL(din_main, dim3(nblocks), dim3(256), 0, stream,
                       query, keys, b0v, ab, ws, out);
}

// Round 3
// 178.140 us; speedup vs baseline: 1.8106x; 1.5552x over previous
//
#include <hip/hip_runtime.h>
#include <math.h>

#define B_TOT 4096
#define T_LEN 200
#define E_DIM 12
#define LOG2E 1.44269504088896340736f

typedef __attribute__((ext_vector_type(8))) short     bf16x8;
typedef __attribute__((ext_vector_type(4))) float     f32x4;

// ---- ws byte layout ----
//  [0      .. 10239]  W0eff  ushort[80][64]   row n (out ch), k fastest
//                      k 0..11 : Wk_eff[i=k][n]   = W0[12+k][n] - W0[24+k][n]
//                      k12..23 : Wqk[i=k-12][n]   = W0[36+i][n]
//                      k24..35 : Wq_eff[i=k-24][n]= W0[i][n]   + W0[24+i][n]
//                      k==36   : b0[n]; else 0
//  [10240  .. 19455]  W1eff  ushort[48][96]   row j, k fastest
//                      j<40: k<80 -> W1[k][j]; k==80 -> b1[j]; else 0
//  [19456  .. 20735]  dice0c float4[80] = {-rs, mm0*rs, a0, 1-a0}, rs=rsqrt(mv0+eps)*log2e
//  [20736  .. 21503]  dice1c float4[48] = {-rs1, mm1*rs1, a1*ak, (1-a1)*ak}, 0 for j>=40

__device__ inline unsigned short f2bf(float f) {
    union { float f; unsigned u; } x; x.f = f;
    unsigned r = x.u + 0x7FFFu + ((x.u >> 16) & 1u);
    return (unsigned short)(r >> 16);
}

__global__ __launch_bounds__(256) void din_prep(
    const float* __restrict__ W0, const float* __restrict__ b0v,
    const float* __restrict__ W1, const float* __restrict__ b1v,
    const float* __restrict__ a0, const float* __restrict__ a1,
    const float* __restrict__ mm0, const float* __restrict__ mv0,
    const float* __restrict__ mm1, const float* __restrict__ mv1,
    const float* __restrict__ ak, void* __restrict__ wsv)
{
    unsigned char* wsb = (unsigned char*)wsv;
    unsigned short* w0e = (unsigned short*)wsb;            // [80*64]
    unsigned short* w1e = (unsigned short*)(wsb + 10240);  // [48*96]
    float* d0c = (float*)(wsb + 19456);                    // [80*4]
    float* d1c = (float*)(wsb + 20736);                    // [48*4]

    int idx = blockIdx.x * 256 + threadIdx.x;              // 0..10239
    if (idx < 5120) {
        int n = idx >> 6, k = idx & 63;
        float v;
        if (k < 12)        v = W0[(12 + k) * 80 + n] - W0[(24 + k) * 80 + n];
        else if (k < 24)   v = W0[(36 + (k - 12)) * 80 + n];
        else if (k < 36)   v = W0[(k - 24) * 80 + n] + W0[(24 + (k - 24)) * 80 + n];
        else if (k == 36)  v = b0v[n];
        else               v = 0.0f;
        w0e[n * 64 + k] = f2bf(v);
    } else if (idx < 9728) {
        int v2 = idx - 5120;
        int n = v2 / 96, k = v2 - n * 96;
        float v = 0.0f;
        if (n < 40) {
            if (k < 80)       v = W1[k * 40 + n];
            else if (k == 80) v = b1v[n];
        }
        w1e[n * 96 + k] = f2bf(v);
    } else if (idx < 10048) {
        int v2 = idx - 9728;
        int o = v2 >> 2, c = v2 & 3;
        float rs = rsqrtf(mv0[o] + 1e-9f) * LOG2E;
        float val = (c == 0) ? -rs : (c == 1) ? mm0[o] * rs : (c == 2) ? a0[o] : 1.0f - a0[o];
        d0c[o * 4 + c] = val;
    } else {
        int v2 = idx - 10048;
        int j = v2 >> 2, c = v2 & 3;
        float val = 0.0f;
        if (j < 40) {
            float rs = rsqrtf(mv1[j] + 1e-9f) * LOG2E;
            val = (c == 0) ? -rs : (c == 1) ? mm1[j] * rs : (c == 2) ? a1[j] * ak[j]
                                                          : (1.0f - a1[j]) * ak[j];
        }
        d1c[j * 4 + c] = val;
    }
}

#define A0_STRIDE 72    // ushorts per row (64 used + 8 pad), 144 B: 16B-aligned rows
#define H_STRIDE  104   // ushorts per row (96 used + 8 pad), 208 B: 16B-aligned rows

__global__ __launch_bounds__(256, 2) void din_mfma(
    const float* __restrict__ query, const float* __restrict__ keys,
    const float* __restrict__ abias_p, const void* __restrict__ wsv,
    float* __restrict__ out)
{
    __shared__ __align__(16) unsigned short A0[256 * A0_STRIDE];  // 36864 B
    __shared__ __align__(16) unsigned short H[4 * 16 * H_STRIDE]; // 13312 B
    __shared__ __align__(16) float SC[256];                       // 1024 B

    const unsigned char* wsb = (const unsigned char*)wsv;
    const unsigned short* w0e = (const unsigned short*)wsb;
    const unsigned short* w1e = (const unsigned short*)(wsb + 10240);
    const f32x4* d0cp = (const f32x4*)(wsb + 19456);
    const f32x4* d1cp = (const f32x4*)(wsb + 20736);

    const int tid = threadIdx.x;
    const int lane = tid & 63;
    const int w = tid >> 6;          // wave id 0..3
    const int lane15 = lane & 15;
    const int quad = lane >> 4;

    const int p = blockIdx.x * 256 + tid;     // global position, grid exact
    const int bq = p / T_LEN;                 // batch index of this thread's position

    // ---- stage A0 row for position p ----
    float kk[12], qq[12];
    {
        const float4* kp = (const float4*)(keys + (size_t)p * E_DIM);
        float4 k0 = kp[0], k1 = kp[1], k2 = kp[2];
        kk[0]=k0.x; kk[1]=k0.y; kk[2]=k0.z; kk[3]=k0.w;
        kk[4]=k1.x; kk[5]=k1.y; kk[6]=k1.z; kk[7]=k1.w;
        kk[8]=k2.x; kk[9]=k2.y; kk[10]=k2.z; kk[11]=k2.w;
        const float4* qp = (const float4*)(query + (size_t)bq * E_DIM);
        float4 q0 = qp[0], q1 = qp[1], q2 = qp[2];
        qq[0]=q0.x; qq[1]=q0.y; qq[2]=q0.z; qq[3]=q0.w;
        qq[4]=q1.x; qq[5]=q1.y; qq[6]=q1.z; qq[7]=q1.w;
        qq[8]=q2.x; qq[9]=q2.y; qq[10]=q2.z; qq[11]=q2.w;
    }
    {
        unsigned short row[64];
        #pragma unroll
        for (int i = 0; i < 12; ++i) row[i]      = f2bf(kk[i]);
        #pragma unroll
        for (int i = 0; i < 12; ++i) row[12 + i] = f2bf(qq[i] * kk[i]);
        #pragma unroll
        for (int i = 0; i < 12; ++i) row[24 + i] = f2bf(qq[i]);
        row[36] = 0x3F80;  // 1.0 bf16
        #pragma unroll
        for (int i = 37; i < 64; ++i) row[i] = 0;
        unsigned short* dst = &A0[tid * A0_STRIDE];
        #pragma unroll
        for (int j = 0; j < 8; ++j) {
            bf16x8 v;
            #pragma unroll
            for (int c = 0; c < 8; ++c) v[c] = (short)row[j * 8 + c];
            *(bf16x8*)(dst + j * 8) = v;
        }
    }

    // ---- load B fragments + dice consts (uniform across positions) ----
    bf16x8 b0f[5][2];
    #pragma unroll
    for (int nt = 0; nt < 5; ++nt)
        #pragma unroll
        for (int ks = 0; ks < 2; ++ks)
            b0f[nt][ks] = *(const bf16x8*)(w0e + (nt * 16 + lane15) * 64 + ks * 32 + quad * 8);
    bf16x8 b1f[3][3];
    #pragma unroll
    for (int nt = 0; nt < 3; ++nt)
        #pragma unroll
        for (int ks = 0; ks < 3; ++ks)
            b1f[nt][ks] = *(const bf16x8*)(w1e + (nt * 16 + lane15) * 96 + ks * 32 + quad * 8);
    f32x4 d0c[5];
    #pragma unroll
    for (int nt = 0; nt < 5; ++nt) d0c[nt] = d0cp[nt * 16 + lane15];
    f32x4 d1c[3];
    #pragma unroll
    for (int nt = 0; nt < 3; ++nt) d1c[nt] = d1cp[nt * 16 + lane15];
    const float abias = abias_p[0];

    // ---- write constant tail of H rows (k=80 -> 1.0, 81..95 -> 0), once ----
    unsigned short* Hw = &H[w * 16 * H_STRIDE];
    if (quad == 0) {
        bf16x8 one8 = {(short)0x3F80, 0, 0, 0, 0, 0, 0, 0};
        bf16x8 zero8 = {0, 0, 0, 0, 0, 0, 0, 0};
        *(bf16x8*)(Hw + lane15 * H_STRIDE + 80) = one8;
        *(bf16x8*)(Hw + lane15 * H_STRIDE + 88) = zero8;
    }
    __syncthreads();   // A0 staged (also covers H tail before first read)

    // ---- 4 position-tiles of 16 per wave ----
    #pragma unroll
    for (int ti = 0; ti < 4; ++ti) {
        const int tt = w * 4 + ti;
        const unsigned short* arow = &A0[(tt * 16 + lane15) * A0_STRIDE + quad * 8];
        bf16x8 a0 = *(const bf16x8*)arow;
        bf16x8 a1 = *(const bf16x8*)(arow + 32);

        // layer 0: [16x64]·[64x80]
        f32x4 acc[5];
        #pragma unroll
        for (int nt = 0; nt < 5; ++nt) {
            f32x4 c = {0.f, 0.f, 0.f, 0.f};
            c = __builtin_amdgcn_mfma_f32_16x16x32_bf16(a0, b0f[nt][0], c, 0, 0, 0);
            c = __builtin_amdgcn_mfma_f32_16x16x32_bf16(a1, b0f[nt][1], c, 0, 0, 0);
            acc[nt] = c;
        }
        // dice0 + write h to LDS (C-layout -> [pos][ch])
        #pragma unroll
        for (int nt = 0; nt < 5; ++nt) {
            #pragma unroll
            for (int r = 0; r < 4; ++r) {
                float z = acc[nt][r];
                float pg = __builtin_amdgcn_rcpf(
                    1.0f + __builtin_amdgcn_exp2f(fmaf(z, d0c[nt].x, d0c[nt].y)));
                float h = z * fmaf(pg, d0c[nt].w, d0c[nt].z);
                Hw[(quad * 4 + r) * H_STRIDE + nt * 16 + lane15] = f2bf(h);
            }
        }
        __syncthreads();

        // layer 1: [16x96]·[96x48]
        bf16x8 af[3];
        #pragma unroll
        for (int ks = 0; ks < 3; ++ks)
            af[ks] = *(const bf16x8*)(Hw + lane15 * H_STRIDE + ks * 32 + quad * 8);
        float s[4] = {0.f, 0.f, 0.f, 0.f};
        #pragma unroll
        for (int nt = 0; nt < 3; ++nt) {
            f32x4 c = {0.f, 0.f, 0.f, 0.f};
            #pragma unroll
            for (int ks = 0; ks < 3; ++ks)
                c = __builtin_amdgcn_mfma_f32_16x16x32_bf16(af[ks], b1f[nt][ks], c, 0, 0, 0);
            #pragma unroll
            for (int r = 0; r < 4; ++r) {
                float z = c[r];
                float pg = __builtin_amdgcn_rcpf(
                    1.0f + __builtin_amdgcn_exp2f(fmaf(z, d1c[nt].x, d1c[nt].y)));
                s[r] = fmaf(z, fmaf(pg, d1c[nt].w, d1c[nt].z), s[r]);
            }
        }
        // sum over the 16 j-columns (lanes within quad)
        #pragma unroll
        for (int m = 1; m < 16; m <<= 1) {
            #pragma unroll
            for (int r = 0; r < 4; ++r) s[r] += __shfl_xor(s[r], m, 64);
        }
        if (lane15 == 0) {
            float4 sv;
            sv.x = s[0] + abias; sv.y = s[1] + abias;
            sv.z = s[2] + abias; sv.w = s[3] + abias;
            *(float4*)&SC[tt * 16 + quad * 4] = sv;
        }
        __syncthreads();
    }

    // ---- phase 2: out[b][e] += sum_t score * keys, segmented per wave ----
    float sc = SC[tid];
    float v[12];
    #pragma unroll
    for (int e = 0; e < 12; ++e) v[e] = sc * kk[e];
    int b0w = __shfl(bq, 0, 64);
    int b63 = __shfl(bq, 63, 64);
    float r0[12], r1[12];
    bool first = (bq == b0w);
    #pragma unroll
    for (int e = 0; e < 12; ++e) {
        r0[e] = first ? v[e] : 0.0f;
        r1[e] = first ? 0.0f : v[e];
    }
    #pragma unroll
    for (int m = 1; m < 64; m <<= 1) {
        #pragma unroll
        for (int e = 0; e < 12; ++e) {
            r0[e] += __shfl_xor(r0[e], m, 64);
            r1[e] += __shfl_xor(r1[e], m, 64);
        }
    }
    if (lane == 0) {
        #pragma unroll
        for (int e = 0; e < 12; ++e)
            atomicAdd(&out[(size_t)b0w * 12 + e], r0[e]);
        if (b63 != b0w) {
            #pragma unroll
            for (int e = 0; e < 12; ++e)
                atomicAdd(&out[(size_t)b63 * 12 + e], r1[e]);
        }
    }
}

extern "C" void kernel_launch(void* const* d_in, const int* in_sizes, int n_in,
                              void* d_out, int out_size, void* d_ws, size_t ws_size,
                              hipStream_t stream) {
    const float* query = (const float*)d_in[0];
    const float* keys  = (const float*)d_in[1];
    // d_in[2] = mask (unused: reference bug matmuls unmasked scores)
    const float* W0  = (const float*)d_in[3];
    const float* b0v = (const float*)d_in[4];
    const float* W1  = (const float*)d_in[5];
    const float* b1v = (const float*)d_in[6];
    const float* a0  = (const float*)d_in[7];
    const float* a1  = (const float*)d_in[8];
    const float* mm0 = (const float*)d_in[9];
    const float* mv0 = (const float*)d_in[10];
    const float* mm1 = (const float*)d_in[11];
    const float* mv1 = (const float*)d_in[12];
    const float* ak  = (const float*)d_in[13];
    const float* ab  = (const float*)d_in[14];
    float* out = (float*)d_out;

    hipMemsetAsync(d_out, 0, (size_t)out_size * sizeof(float), stream);
    hipLaunchKernelGGL(din_prep, dim3(40), dim3(256), 0, stream,
                       W0, b0v, W1, b1v, a0, a1, mm0, mv0, mm1, mv1, ak, d_ws);
    hipLaunchKernelGGL(din_mfma, dim3(3200), dim3(256), 0, stream,
                       query, keys, ab, d_ws, out);
}

// Round 4
// 155.858 us; speedup vs baseline: 2.0694x; 1.1430x over previous
//
#include <hip/hip_runtime.h>
#include <math.h>

#define B_TOT 4096
#define T_LEN 200
#define E_DIM 12
#define LOG2E 1.44269504088896340736f

typedef __attribute__((ext_vector_type(8))) short bf16x8;
typedef __attribute__((ext_vector_type(4))) float f32x4;

// ---- ws byte layout (unchanged from R3) ----
//  [0      .. 10239]  W0eff  ushort[80][64]   row n, k fastest
//                      k0..11: Wk_eff; k12..23: Wqk; k24..35: Wq_eff; k36: b0; else 0
//  [10240  .. 19455]  W1eff  ushort[48][96]   row j: k<80 -> W1[k][j]; k80 -> b1[j]; else 0
//  [19456  .. 20735]  dice0c float4[80] = {-rs, mm0*rs, a0, 1-a0}
//  [20736  .. 21503]  dice1c float4[48] = {-rs1, mm1*rs1, a1*ak, (1-a1)*ak}

__device__ inline unsigned short f2bf(float f) {
    union { float f; unsigned u; } x; x.f = f;
    unsigned r = x.u + 0x7FFFu + ((x.u >> 16) & 1u);
    return (unsigned short)(r >> 16);
}

__global__ __launch_bounds__(256) void din_prep(
    const float* __restrict__ W0, const float* __restrict__ b0v,
    const float* __restrict__ W1, const float* __restrict__ b1v,
    const float* __restrict__ a0, const float* __restrict__ a1,
    const float* __restrict__ mm0, const float* __restrict__ mv0,
    const float* __restrict__ mm1, const float* __restrict__ mv1,
    const float* __restrict__ ak, void* __restrict__ wsv)
{
    unsigned char* wsb = (unsigned char*)wsv;
    unsigned short* w0e = (unsigned short*)wsb;
    unsigned short* w1e = (unsigned short*)(wsb + 10240);
    float* d0c = (float*)(wsb + 19456);
    float* d1c = (float*)(wsb + 20736);

    int idx = blockIdx.x * 256 + threadIdx.x;
    if (idx < 5120) {
        int n = idx >> 6, k = idx & 63;
        float v;
        if (k < 12)        v = W0[(12 + k) * 80 + n] - W0[(24 + k) * 80 + n];
        else if (k < 24)   v = W0[(36 + (k - 12)) * 80 + n];
        else if (k < 36)   v = W0[(k - 24) * 80 + n] + W0[(24 + (k - 24)) * 80 + n];
        else if (k == 36)  v = b0v[n];
        else               v = 0.0f;
        w0e[n * 64 + k] = f2bf(v);
    } else if (idx < 9728) {
        int v2 = idx - 5120;
        int n = v2 / 96, k = v2 - n * 96;
        float v = 0.0f;
        if (n < 40) {
            if (k < 80)       v = W1[k * 40 + n];
            else if (k == 80) v = b1v[n];
        }
        w1e[n * 96 + k] = f2bf(v);
    } else if (idx < 10048) {
        int v2 = idx - 9728;
        int o = v2 >> 2, c = v2 & 3;
        float rs = rsqrtf(mv0[o] + 1e-9f) * LOG2E;
        float val = (c == 0) ? -rs : (c == 1) ? mm0[o] * rs : (c == 2) ? a0[o] : 1.0f - a0[o];
        d0c[o * 4 + c] = val;
    } else {
        int v2 = idx - 10048;
        int j = v2 >> 2, c = v2 & 3;
        float val = 0.0f;
        if (j < 40) {
            float rs = rsqrtf(mv1[j] + 1e-9f) * LOG2E;
            val = (c == 0) ? -rs : (c == 1) ? mm1[j] * rs : (c == 2) ? a1[j] * ak[j]
                                                          : (1.0f - a1[j]) * ak[j];
        }
        d1c[j * 4 + c] = val;
    }
}

#define A0_STRIDE 72    // ushorts/row (64 data + 8 pad); 144 B: 16B-aligned, even bank spread
#define H_STRIDE  104   // ushorts/row (96 data + 8 pad); 208 B: 16B-aligned

// One batch per wave; everything wave-private -> ZERO __syncthreads.
__global__ __launch_bounds__(256, 2) void din_mfma(
    const float* __restrict__ query, const float* __restrict__ keys,
    const float* __restrict__ abias_p, const void* __restrict__ wsv,
    float* __restrict__ out)
{
    // Aseg FIRST so its garbage frag-reads (rows 1..15) land in A0, in-block.
    __shared__ __align__(16) unsigned short Aseg[4 * 64];            //   512 B
    __shared__ __align__(16) unsigned short A0[4 * 64 * A0_STRIDE];  // 36864 B
    __shared__ __align__(16) unsigned short H[4 * 16 * H_STRIDE];    // 13312 B

    const unsigned char* wsb = (const unsigned char*)wsv;
    const unsigned short* w0e = (const unsigned short*)wsb;
    const unsigned short* w1e = (const unsigned short*)(wsb + 10240);
    const f32x4* d0cp = (const f32x4*)(wsb + 19456);
    const f32x4* d1cp = (const f32x4*)(wsb + 20736);

    const int tid = threadIdx.x;
    const int lane = tid & 63;
    const int w = tid >> 6;
    const int l15 = lane & 15;
    const int quad = lane >> 4;
    const int b = blockIdx.x * 4 + w;          // batch of this wave

    unsigned short* A0w = &A0[w * 64 * A0_STRIDE];
    unsigned short* Hw  = &H[w * 16 * H_STRIDE];
    unsigned short* Asw = &Aseg[w * 64];

    // ---- weight fragments + dice consts (loop-invariant) ----
    bf16x8 b0f[5][2];
    #pragma unroll
    for (int nt = 0; nt < 5; ++nt)
        #pragma unroll
        for (int ks = 0; ks < 2; ++ks)
            b0f[nt][ks] = *(const bf16x8*)(w0e + (nt * 16 + l15) * 64 + ks * 32 + quad * 8);
    bf16x8 b1f[3][3];
    #pragma unroll
    for (int nt = 0; nt < 3; ++nt)
        #pragma unroll
        for (int ks = 0; ks < 3; ++ks)
            b1f[nt][ks] = *(const bf16x8*)(w1e + (nt * 16 + l15) * 96 + ks * 32 + quad * 8);
    f32x4 d0c[5];
    #pragma unroll
    for (int nt = 0; nt < 5; ++nt) d0c[nt] = d0cp[nt * 16 + l15];
    f32x4 d1c[3];
    #pragma unroll
    for (int nt = 0; nt < 3; ++nt) d1c[nt] = d1cp[nt * 16 + l15];
    const float abias = abias_p[0];

    // ---- per-batch query (all lanes same row: broadcast loads) ----
    float qq[12];
    {
        const float4* qp = (const float4*)(query + (size_t)b * E_DIM);
        float4 q0 = qp[0], q1 = qp[1], q2 = qp[2];
        qq[0]=q0.x; qq[1]=q0.y; qq[2]=q0.z; qq[3]=q0.w;
        qq[4]=q1.x; qq[5]=q1.y; qq[6]=q1.z; qq[7]=q1.w;
        qq[8]=q2.x; qq[9]=q2.y; qq[10]=q2.z; qq[11]=q2.w;
    }
    unsigned qqw[6];
    #pragma unroll
    for (int i = 0; i < 6; ++i)
        qqw[i] = (unsigned)f2bf(qq[2 * i]) | ((unsigned)f2bf(qq[2 * i + 1]) << 16);

    // ---- H constant tail: k=80 -> 1.0, 81..95 -> 0 (per row) ----
    if (quad == 0) {
        bf16x8 one8 = {(short)0x3F80, 0, 0, 0, 0, 0, 0, 0};
        bf16x8 zero8 = {0, 0, 0, 0, 0, 0, 0, 0};
        *(bf16x8*)(Hw + l15 * H_STRIDE + 80) = one8;
        *(bf16x8*)(Hw + l15 * H_STRIDE + 88) = zero8;
    }

    f32x4 acc2 = {0.f, 0.f, 0.f, 0.f};   // phase-2 accumulator: C[0][e] = sum sc*k

    for (int c = 0; c < 4; ++c) {
        const int t0 = c * 64;
        const int myT = t0 + lane;
        const bool valid = myT < T_LEN;

        // ---- stage A0 row for this lane's position ----
        float kk[12];
        if (valid) {
            const float4* kp = (const float4*)(keys + ((size_t)b * T_LEN + myT) * E_DIM);
            float4 k0 = kp[0], k1 = kp[1], k2 = kp[2];
            kk[0]=k0.x; kk[1]=k0.y; kk[2]=k0.z; kk[3]=k0.w;
            kk[4]=k1.x; kk[5]=k1.y; kk[6]=k1.z; kk[7]=k1.w;
            kk[8]=k2.x; kk[9]=k2.y; kk[10]=k2.z; kk[11]=k2.w;
        } else {
            #pragma unroll
            for (int i = 0; i < 12; ++i) kk[i] = 0.0f;
        }
        {
            unsigned wds[32];
            #pragma unroll
            for (int i = 0; i < 6; ++i)
                wds[i] = (unsigned)f2bf(kk[2 * i]) | ((unsigned)f2bf(kk[2 * i + 1]) << 16);
            #pragma unroll
            for (int i = 0; i < 6; ++i)
                wds[6 + i] = (unsigned)f2bf(qq[2 * i] * kk[2 * i])
                           | ((unsigned)f2bf(qq[2 * i + 1] * kk[2 * i + 1]) << 16);
            #pragma unroll
            for (int i = 0; i < 6; ++i) wds[12 + i] = qqw[i];
            wds[18] = 0x00003F80u;  // k36 = 1.0 (bias lane)
            #pragma unroll
            for (int i = 19; i < 32; ++i) wds[i] = 0u;
            unsigned short* dst = A0w + lane * A0_STRIDE;
            #pragma unroll
            for (int v = 0; v < 8; ++v) {
                bf16x8 pk;
                #pragma unroll
                for (int h = 0; h < 4; ++h) {
                    unsigned u = wds[v * 4 + h];
                    pk[2 * h]     = (short)(u & 0xFFFF);
                    pk[2 * h + 1] = (short)(u >> 16);
                }
                *(bf16x8*)(dst + v * 8) = pk;
            }
        }
        Asw[lane] = 0;   // ensure stale scores cleared (chunk 3 covers only tile 0)

        const int ntiles = (c < 3) ? 4 : 1;
        for (int ti = 0; ti < ntiles; ++ti) {
            const unsigned short* ar = A0w + (ti * 16 + l15) * A0_STRIDE + quad * 8;
            bf16x8 a0 = *(const bf16x8*)ar;
            bf16x8 a1 = *(const bf16x8*)(ar + 32);

            // layer 0: [16x64]·[64x80]
            f32x4 acc[5];
            #pragma unroll
            for (int nt = 0; nt < 5; ++nt) {
                f32x4 cc = {0.f, 0.f, 0.f, 0.f};
                cc = __builtin_amdgcn_mfma_f32_16x16x32_bf16(a0, b0f[nt][0], cc, 0, 0, 0);
                cc = __builtin_amdgcn_mfma_f32_16x16x32_bf16(a1, b0f[nt][1], cc, 0, 0, 0);
                acc[nt] = cc;
            }
            // dice0 -> H ([pos][ch])
            #pragma unroll
            for (int nt = 0; nt < 5; ++nt) {
                #pragma unroll
                for (int r = 0; r < 4; ++r) {
                    float z = acc[nt][r];
                    float pg = __builtin_amdgcn_rcpf(
                        1.0f + __builtin_amdgcn_exp2f(fmaf(z, d0c[nt].x, d0c[nt].y)));
                    float h = z * fmaf(pg, d0c[nt].w, d0c[nt].z);
                    Hw[(quad * 4 + r) * H_STRIDE + nt * 16 + l15] = f2bf(h);
                }
            }
            // layer 1: [16x96]·[96x48]
            bf16x8 af[3];
            #pragma unroll
            for (int ks = 0; ks < 3; ++ks)
                af[ks] = *(const bf16x8*)(Hw + l15 * H_STRIDE + ks * 32 + quad * 8);
            float s[4] = {0.f, 0.f, 0.f, 0.f};
            #pragma unroll
            for (int nt = 0; nt < 3; ++nt) {
                f32x4 cc = {0.f, 0.f, 0.f, 0.f};
                #pragma unroll
                for (int ks = 0; ks < 3; ++ks)
                    cc = __builtin_amdgcn_mfma_f32_16x16x32_bf16(af[ks], b1f[nt][ks], cc, 0, 0, 0);
                #pragma unroll
                for (int r = 0; r < 4; ++r) {
                    float z = cc[r];
                    float pg = __builtin_amdgcn_rcpf(
                        1.0f + __builtin_amdgcn_exp2f(fmaf(z, d1c[nt].x, d1c[nt].y)));
                    s[r] = fmaf(z, fmaf(pg, d1c[nt].w, d1c[nt].z), s[r]);
                }
            }
            // sum over 16 j-cols
            #pragma unroll
            for (int m = 1; m < 16; m <<= 1) {
                #pragma unroll
                for (int r = 0; r < 4; ++r) s[r] += __shfl_xor(s[r], m, 64);
            }
            // scores (bf16) -> Aseg row 0, invalid positions masked to 0
            if (l15 == 0) {
                unsigned long long pk = 0ull;
                #pragma unroll
                for (int r = 0; r < 4; ++r) {
                    int t = t0 + ti * 16 + quad * 4 + r;
                    unsigned short sb = (t < T_LEN) ? f2bf(s[r] + abias) : (unsigned short)0;
                    pk |= (unsigned long long)sb << (16 * r);
                }
                *(unsigned long long*)(Asw + ti * 16 + quad * 4) = pk;
            }
        }

        // ---- phase 2 partial: C[0][e] += scores · keys (2 MFMA, K=64) ----
        #pragma unroll
        for (int ks = 0; ks < 2; ++ks) {
            // A frag: row l15 (only row 0 real; others garbage, C rows 1..15 unread)
            bf16x8 pa = *(const bf16x8*)(Asw + l15 * 64 + ks * 32 + quad * 8);
            // B frag: B[k=pos][n=e] = A0 column l15 (cols 12..15 garbage, unread)
            bf16x8 bk;
            #pragma unroll
            for (int j = 0; j < 8; ++j)
                bk[j] = (short)A0w[(ks * 32 + quad * 8 + j) * A0_STRIDE + l15];
            acc2 = __builtin_amdgcn_mfma_f32_16x16x32_bf16(pa, bk, acc2, 0, 0, 0);
        }
    }

    // ---- epilogue: C row 0 = quad 0, reg 0; cols 0..11 = e ----
    if (quad == 0 && l15 < 12)
        out[(size_t)b * E_DIM + l15] = acc2[0];
}

extern "C" void kernel_launch(void* const* d_in, const int* in_sizes, int n_in,
                              void* d_out, int out_size, void* d_ws, size_t ws_size,
                              hipStream_t stream) {
    const float* query = (const float*)d_in[0];
    const float* keys  = (const float*)d_in[1];
    // d_in[2] = mask (unused: reference bug matmuls unmasked scores)
    const float* W0  = (const float*)d_in[3];
    const float* b0v = (const float*)d_in[4];
    const float* W1  = (const float*)d_in[5];
    const float* b1v = (const float*)d_in[6];
    const float* a0  = (const float*)d_in[7];
    const float* a1  = (const float*)d_in[8];
    const float* mm0 = (const float*)d_in[9];
    const float* mv0 = (const float*)d_in[10];
    const float* mm1 = (const float*)d_in[11];
    const float* mv1 = (const float*)d_in[12];
    const float* ak  = (const float*)d_in[13];
    const float* ab  = (const float*)d_in[14];
    float* out = (float*)d_out;

    hipLaunchKernelGGL(din_prep, dim3(40), dim3(256), 0, stream,
                       W0, b0v, W1, b1v, a0, a1, mm0, mv0, mm1, mv1, ak, d_ws);
    hipLaunchKernelGGL(din_mfma, dim3(B_TOT / 4), dim3(256), 0, stream,
                       query, keys, ab, d_ws, out);
}